// Round 1
// baseline (39.000 us; speedup 1.0000x reference)
//
#include <hip/hip_runtime.h>

#define HID   64
#define NHD   8
#define ITILE 8
#define JBLK  256

// out[b,k,i,j] = sum_h relu( (u_j[h]+b1[h]) - u_i[h] ) * W2[h,k] + b2[k]
// where u_n = p_n @ W1, p_n = xyz[b,:,n].
__global__ __launch_bounds__(JBLK) void relposenc_fused(
    const float* __restrict__ xyz, const float* __restrict__ W1,
    const float* __restrict__ b1,  const float* __restrict__ W2,
    const float* __restrict__ b2,  float* __restrict__ out, int N) {

  __shared__ __align__(16) float sUi[HID][ITILE];  // u_i[h][ii] (raw, no b1)
  __shared__ __align__(16) float sW2[HID][NHD];

  const int tid = threadIdx.x;
  const int j   = blockIdx.x * JBLK + tid;
  const int i0  = blockIdx.y * ITILE;
  const int b   = blockIdx.z;

  const float* xb = xyz + (size_t)b * 3 * N;

  // ---- stage W2 (64x8) into LDS ----
  #pragma unroll
  for (int r = 0; r < (HID * NHD) / JBLK; ++r) {
    int t = tid + r * JBLK;
    sW2[t / NHD][t % NHD] = W2[t];
  }
  // ---- compute + stage u_i for the 8 i's of this block ----
  #pragma unroll
  for (int r = 0; r < (HID * ITILE) / JBLK; ++r) {
    int t  = tid + r * JBLK;
    int h  = t / ITILE;
    int ii = t % ITILE;
    int i  = i0 + ii;
    float x0 = xb[0 * N + i], x1 = xb[1 * N + i], x2 = xb[2 * N + i];
    sUi[h][ii] = fmaf(x0, W1[0 * HID + h],
                 fmaf(x1, W1[1 * HID + h],
                      x2 * W1[2 * HID + h]));
  }
  __syncthreads();

  // this thread's point (for the j role)
  const float x0 = xb[0 * N + j];
  const float x1 = xb[1 * N + j];
  const float x2 = xb[2 * N + j];

  float acc[ITILE][NHD];
  #pragma unroll
  for (int ii = 0; ii < ITILE; ++ii)
    #pragma unroll
    for (int k = 0; k < NHD; ++k) acc[ii][k] = 0.f;

  #pragma unroll 4
  for (int h = 0; h < HID; ++h) {
    // a_j[h] = u_j[h] + b1[h]  (W1/b1 reads are wave-uniform -> s_load)
    float aj = fmaf(x0, W1[0 * HID + h],
               fmaf(x1, W1[1 * HID + h],
               fmaf(x2, W1[2 * HID + h], b1[h])));

    const float4* pu = (const float4*)&sUi[h][0];
    const float4* pw = (const float4*)&sW2[h][0];
    float4 u0 = pu[0], u1 = pu[1];   // broadcast ds_read_b128, no conflicts
    float4 w0 = pw[0], w1 = pw[1];
    float uu[ITILE] = {u0.x, u0.y, u0.z, u0.w, u1.x, u1.y, u1.z, u1.w};
    float ww[NHD]   = {w0.x, w0.y, w0.z, w0.w, w1.x, w1.y, w1.z, w1.w};

    #pragma unroll
    for (int ii = 0; ii < ITILE; ++ii) {
      float v = aj - uu[ii];
      v = v > 0.f ? v : 0.f;           // relu
      #pragma unroll
      for (int k = 0; k < NHD; ++k)
        acc[ii][k] = fmaf(v, ww[k], acc[ii][k]);
    }
  }

  // ---- epilogue: out[((b*8+k)*N + i)*N + j], j contiguous -> coalesced ----
  #pragma unroll
  for (int k = 0; k < NHD; ++k) {
    const float bk = b2[k];
    #pragma unroll
    for (int ii = 0; ii < ITILE; ++ii) {
      out[(((size_t)(b * NHD + k)) * N + (i0 + ii)) * N + j] = acc[ii][k] + bk;
    }
  }
}

extern "C" void kernel_launch(void* const* d_in, const int* in_sizes, int n_in,
                              void* d_out, int out_size, void* d_ws, size_t ws_size,
                              hipStream_t stream) {
  const float* xyz = (const float*)d_in[0];
  const float* W1  = (const float*)d_in[1];
  const float* b1  = (const float*)d_in[2];
  const float* W2  = (const float*)d_in[3];
  const float* b2  = (const float*)d_in[4];
  float* out = (float*)d_out;

  // in_sizes[0] = B*3*N ; out_size = B*8*N*N  =>  N = 3*out/(8*in0)
  const long long in0 = in_sizes[0];
  const int N = (int)((3LL * (long long)out_size) / (8LL * in0));
  const int B = (int)(in0 / (3LL * N));

  dim3 grid(N / JBLK, N / ITILE, B);
  relposenc_fused<<<grid, JBLK, 0, stream>>>(xyz, W1, b1, W2, b2, out, N);
}

// Round 2
// 24.313 us; speedup vs baseline: 1.6041x; 1.6041x over previous
//
#include <hip/hip_runtime.h>
#include <hip/hip_bf16.h>

#define HID   64
#define NHD   8
#define IT    16          // i's per block
#define WAVES 8
#define JTW   32          // j's per wave (2 tiles of 16)
#define JT    (WAVES*JTW) // 256 j's per block

typedef __attribute__((ext_vector_type(8))) short bf16x8;
typedef __attribute__((ext_vector_type(4))) float f32x4;

static __device__ __forceinline__ short f2bf(float f) {
  __hip_bfloat16 h = __float2bfloat16(f);
  short s; __builtin_memcpy(&s, &h, sizeof(s));
  return s;
}

// out[b,k,i,j] = sum_h relu( (u_j[h]+b1[h]) - u_i[h] ) * W2[h,k] + b2[k]
// MFMA 16x16x32 bf16:  A = W2^T (M=16 head-rows, 8 used),  B = relu-diff (N=16 j's),
// accumulate over K=64 (2 mfma). D: col=lane&15=j, row=(lane>>4)*4+reg=k (verified layout)
// -> stores are j-contiguous 64B segments, lanes>=32 (k>=8) masked off.
__global__ __launch_bounds__(WAVES * 64, 4) void relposenc_mfma(
    const float* __restrict__ xyz, const float* __restrict__ W1,
    const float* __restrict__ b1,  const float* __restrict__ W2,
    const float* __restrict__ b2,  float* __restrict__ out, int N) {

  __shared__ float sW1b1[4][HID];   // rows 0-2: W1, row 3: b1
  __shared__ float sU[IT][HID];     // u_i (no bias)

  const int tid  = threadIdx.x;
  const int wave = tid >> 6;
  const int lane = tid & 63;
  const int col  = lane & 15;       // j-within-tile (B/D col) and head-row (A)
  const int hgrp = lane >> 4;       // 0..3 : k-slice group
  const int b    = blockIdx.z;
  const int i0   = blockIdx.y * IT;
  const int j0   = blockIdx.x * JT + wave * JTW;

  const float* xb = xyz + (size_t)b * 3 * N;

  // ---- stage W1/b1 into LDS ----
  if (tid < 4 * HID) {
    int r = tid >> 6, h = tid & 63;
    sW1b1[r][h] = (r < 3) ? W1[r * HID + h] : b1[h];
  }
  // ---- stage u_i for the block's 16 i's (reads W1 from global; L2-hot) ----
  for (int t = tid; t < IT * HID; t += WAVES * 64) {
    int ii = t >> 6, h = t & 63;
    int i  = i0 + ii;
    sU[ii][h] = fmaf(xb[i], W1[h],
                fmaf(xb[N + i], W1[HID + h],
                     xb[2 * N + i] * W1[2 * HID + h]));
  }

  // ---- A fragments: W2^T, rows 8..15 zero-padded (once per block) ----
  bf16x8 afrag[2];
  #pragma unroll
  for (int kb = 0; kb < 2; ++kb)
    #pragma unroll
    for (int e = 0; e < 8; ++e) {
      int h = kb * 32 + hgrp * 8 + e;
      float w = (col < NHD) ? W2[h * NHD + col] : 0.f;
      afrag[kb][e] = f2bf(w);
    }
  // ---- per-lane b2 for the 4 D-rows this lane stores ----
  float b2v[4];
  #pragma unroll
  for (int r = 0; r < 4; ++r) b2v[r] = b2[(hgrp * 4 + r) & 7];

  __syncthreads();

  // ---- per-lane a_j = u_j + b1 at this lane's h-slices, for its 2 j's ----
  float aj[2][2][8];
  #pragma unroll
  for (int t = 0; t < 2; ++t) {
    int j = j0 + t * 16 + col;
    float x0 = xb[j], x1 = xb[N + j], x2 = xb[2 * N + j];
    #pragma unroll
    for (int kb = 0; kb < 2; ++kb)
      #pragma unroll
      for (int e = 0; e < 8; ++e) {
        int h = kb * 32 + hgrp * 8 + e;
        aj[t][kb][e] = fmaf(x0, sW1b1[0][h],
                       fmaf(x1, sW1b1[1][h],
                       fmaf(x2, sW1b1[2][h], sW1b1[3][h])));
      }
  }

  // ---- main i-loop ----
  for (int ii = 0; ii < IT; ++ii) {
    const float4* pu = (const float4*)(&sU[ii][0]);
    float4 u0 = pu[hgrp * 2], u1 = pu[hgrp * 2 + 1];
    float4 u2 = pu[8 + hgrp * 2], u3 = pu[8 + hgrp * 2 + 1];
    float ui[2][8] = {{u0.x,u0.y,u0.z,u0.w, u1.x,u1.y,u1.z,u1.w},
                      {u2.x,u2.y,u2.z,u2.w, u3.x,u3.y,u3.z,u3.w}};
    const int i = i0 + ii;

    #pragma unroll
    for (int t = 0; t < 2; ++t) {
      f32x4 c = {0.f, 0.f, 0.f, 0.f};
      #pragma unroll
      for (int kb = 0; kb < 2; ++kb) {
        bf16x8 bf;
        #pragma unroll
        for (int e = 0; e < 8; ++e) {
          float v = aj[t][kb][e] - ui[kb][e];
          bf[e] = f2bf(v > 0.f ? v : 0.f);
        }
        c = __builtin_amdgcn_mfma_f32_16x16x32_bf16(afrag[kb], bf, c, 0, 0, 0);
      }
      if (lane < 32) {
        size_t jj = (size_t)j0 + t * 16 + col;
        #pragma unroll
        for (int r = 0; r < 4; ++r) {
          int k = hgrp * 4 + r;
          out[(((size_t)(b * NHD + k)) * N + i) * N + jj] = c[r] + b2v[r];
        }
      }
    }
  }
}

extern "C" void kernel_launch(void* const* d_in, const int* in_sizes, int n_in,
                              void* d_out, int out_size, void* d_ws, size_t ws_size,
                              hipStream_t stream) {
  const float* xyz = (const float*)d_in[0];
  const float* W1  = (const float*)d_in[1];
  const float* b1  = (const float*)d_in[2];
  const float* W2  = (const float*)d_in[3];
  const float* b2  = (const float*)d_in[4];
  float* out = (float*)d_out;

  const long long in0 = in_sizes[0];
  const int N = (int)((3LL * (long long)out_size) / (8LL * in0));
  const int B = (int)(in0 / (3LL * N));

  dim3 grid(N / JT, N / IT, B);
  relposenc_mfma<<<grid, WAVES * 64, 0, stream>>>(xyz, W1, b1, W2, b2, out, N);
}